// Round 1
// baseline (722.037 us; speedup 1.0000x reference)
//
#include <hip/hip_runtime.h>
#include <hip/hip_bf16.h>

#define T_ 128
#define N_ 256
#define L_ 256
#define H_ 256
#define COND_ 64

typedef __bf16 bf8_t __attribute__((ext_vector_type(8)));
typedef float f32x4 __attribute__((ext_vector_type(4)));

__device__ __forceinline__ float b2f(unsigned short s) {
    union { unsigned int u; float f; } v; v.u = ((unsigned int)s) << 16; return v.f;
}
__device__ __forceinline__ unsigned short f2b(float f) {
    union { float f; unsigned int u; } v; v.f = f;
    unsigned int r = v.u + 0x7fffu + ((v.u >> 16) & 1u);
    return (unsigned short)(r >> 16);
}
__device__ __forceinline__ void async_copy16(void* lds, const void* g) {
    __builtin_amdgcn_global_load_lds(
        (const __attribute__((address_space(1))) unsigned int*)g,
        (__attribute__((address_space(3))) unsigned int*)lds, 16, 0, 0);
}
__device__ __forceinline__ float frcp(float x) { return __builtin_amdgcn_rcpf(x); }
__device__ __forceinline__ float fsig(float x) { return frcp(1.f + __expf(-x)); }
__device__ __forceinline__ float ftanh_(float x) { return 2.f * fsig(2.f * x) - 1.f; }

// ---------- small prep kernels ----------
__global__ void k_cast(const float* W, unsigned short* O, int n) {
    int i = blockIdx.x * 256 + threadIdx.x;
    if (i < n) O[i] = f2b(W[i]);
}
// Wt[j][k] = bf16(W[k][j]); W is Kd x Jd row-major
__global__ void k_tcast(const float* W, unsigned short* Wt, int Kd, int Jd) {
    int idx = blockIdx.x * 256 + threadIdx.x;
    if (idx >= Kd * Jd) return;
    int j = idx / Kd, k = idx % Kd;
    Wt[idx] = f2b(W[k * Jd + j]);
}
// dense t=0 read: r0 = p_init @ M, cc0 = p_init . C
__global__ void k_r0(const float* M, const float* C, const float* p0,
                     float* r0, float* cc0) {
    int n = blockIdx.x; int tid = threadIdx.x;
    __shared__ float pinit[L_];
    __shared__ float red[256];
    __shared__ int nz;
    if (tid == 0) nz = 0;
    __syncthreads();
    float p = p0[n * L_ + tid];
    if (p != 0.f) atomicAdd(&nz, 1);
    pinit[tid] = p;
    __syncthreads();
    if (tid == 0 && nz == 0) pinit[0] = 1.0f;
    __syncthreads();
    float acc = 0.f;
    for (int l = 0; l < L_; ++l) {
        float s = pinit[l];
        if (s != 0.f) acc += s * M[((size_t)n * L_ + l) * H_ + tid];
    }
    r0[n * H_ + tid] = acc;
    red[tid] = pinit[tid] * C[n * L_ + tid];
    __syncthreads();
    for (int s = 128; s > 0; s >>= 1) { if (tid < s) red[tid] += red[tid + s]; __syncthreads(); }
    if (tid == 0) cc0[n] = red[0];
}
__global__ void k_cc(const float* C, const int* act, const float* cc0, float* cc) {
    int idx = blockIdx.x * 256 + threadIdx.x;
    int t = idx / N_, n = idx % N_;
    cc[idx] = (t == 0) ? cc0[n] : C[n * L_ + act[(t - 1) * N_ + n]];
}
// xin[m][0:64]=cond, [64:320]=r (gather / dense t=0), bf16
__global__ void k_xin(const float* cond, const float* M, const float* r0,
                      const int* act, unsigned short* xin) {
    int idx = blockIdx.x * 256 + threadIdx.x;   // m*320+j
    int m = idx / 320, j = idx % 320;
    int t = m / N_, n = m % N_;
    float v;
    if (j < COND_) v = cond[(size_t)m * COND_ + j];
    else {
        int h = j - COND_;
        v = (t == 0) ? r0[n * H_ + h]
                     : M[((size_t)n * L_ + act[(t - 1) * N_ + n]) * H_ + h];
    }
    xin[(size_t)m * 320 + j] = f2b(v);
}

// ---------- bf16 MFMA GEMM: D = act(A @ Bt^T + bias), A[M][K], Bt[N][K] ----------
template<int RELU>
__global__ __launch_bounds__(256, 2)
void k_gemm(const unsigned short* A, const unsigned short* Bt, const float* bias,
            unsigned short* D, int Ndim, int Kdim) {
    __shared__ __align__(16) unsigned short sA[128 * 64];
    __shared__ __align__(16) unsigned short sB[128 * 64];
    int tid = threadIdx.x;
    int m0 = blockIdx.y * 128, n0 = blockIdx.x * 128;
    int wave = tid >> 6, lane = tid & 63;
    int wm = (wave & 1) * 64, wn = (wave >> 1) * 64;
    int lrow = lane & 15, quad = lane >> 4;
    f32x4 acc[4][4] = {};
    int kIters = Kdim / 64;
    for (int kt = 0; kt < kIters; ++kt) {
        __syncthreads();
        #pragma unroll
        for (int i = 0; i < 4; ++i) {            // A: 1024 x 16B chunks, XOR-swizzled
            int q = i * 256 + tid;
            int row = q >> 3, c = q & 7, sc = c ^ (row & 7);
            async_copy16((char*)sA + q * 16,
                         A + (size_t)(m0 + row) * Kdim + kt * 64 + sc * 8);
        }
        #pragma unroll
        for (int i = 0; i < 4; ++i) {            // B
            int q = i * 256 + tid;
            int row = q >> 3, c = q & 7, sc = c ^ (row & 7);
            async_copy16((char*)sB + q * 16,
                         Bt + (size_t)(n0 + row) * Kdim + kt * 64 + sc * 8);
        }
        __syncthreads();
        #pragma unroll
        for (int kc = 0; kc < 2; ++kc) {
            bf8_t af[4], bfr[4];
            #pragma unroll
            for (int mt = 0; mt < 4; ++mt) {
                int row = wm + mt * 16 + lrow;
                int phys = (kc * 4 + quad) ^ (row & 7);
                af[mt] = *(const bf8_t*)(sA + row * 64 + phys * 8);
            }
            #pragma unroll
            for (int nt = 0; nt < 4; ++nt) {
                int row = wn + nt * 16 + lrow;
                int phys = (kc * 4 + quad) ^ (row & 7);
                bfr[nt] = *(const bf8_t*)(sB + row * 64 + phys * 8);
            }
            #pragma unroll
            for (int mt = 0; mt < 4; ++mt)
                #pragma unroll
                for (int nt = 0; nt < 4; ++nt)
                    acc[mt][nt] = __builtin_amdgcn_mfma_f32_16x16x32_bf16(
                        af[mt], bfr[nt], acc[mt][nt], 0, 0, 0);
        }
    }
    #pragma unroll
    for (int nt = 0; nt < 4; ++nt) {
        int ncol = n0 + wn + nt * 16 + lrow;
        float bv = bias[ncol];
        #pragma unroll
        for (int mt = 0; mt < 4; ++mt)
            #pragma unroll
            for (int r = 0; r < 4; ++r) {
                int mrow = m0 + wm + mt * 16 + quad * 4 + r;
                float v = acc[mt][nt][r] + bv;
                if (RELU) v = v > 0.f ? v : 0.f;
                D[(size_t)mrow * Ndim + ncol] = f2b(v);
            }
    }
}

// ---------- phase B: sequential GRU, 16 blocks x 16 rows, W_hh register-resident ----------
#define HPAD 280
__global__ __launch_bounds__(512, 2)
void k_gru(const unsigned short* gi, const unsigned short* Whh, const float* bhh,
           const float* h0, float* out, unsigned short* h_sbf) {
    int n0 = blockIdx.x * 16;
    int tid = threadIdx.x, wave = tid >> 6, lane = tid & 63;
    int lj = lane & 15, quad = lane >> 4;
    __shared__ __align__(16) unsigned short gibuf[2][16 * 768];
    __shared__ __align__(16) unsigned short hbf[2][16 * HPAD];
    // preload W_hh fragments: wave owns gate-cols wave*32+s*16+lj for each gate
    bf8_t wf[3][2][8];
    float bh[3][2];
    #pragma unroll
    for (int g = 0; g < 3; ++g)
        #pragma unroll
        for (int s = 0; s < 2; ++s) {
            int j = g * 256 + wave * 32 + s * 16 + lj;
            bh[g][s] = bhh[j];
            #pragma unroll
            for (int kc = 0; kc < 8; ++kc)
                wf[g][s][kc] = *(const bf8_t*)(Whh + (size_t)j * 256 + kc * 32 + quad * 8);
        }
    float hreg[2][4];
    #pragma unroll
    for (int s = 0; s < 2; ++s)
        #pragma unroll
        for (int r = 0; r < 4; ++r)
            hreg[s][r] = h0[(size_t)(n0 + quad * 4 + r) * 256 + wave * 32 + s * 16 + lj];
    // stage h0 -> hbf[0]
    for (int i = 0; i < 8; ++i) {
        int idx = i * 512 + tid;     // n*256+j
        int n = idx >> 8, j = idx & 255;
        hbf[0][n * HPAD + j] = f2b(h0[(size_t)(n0 + n) * 256 + j]);
    }
    // preload gi[0]
    #pragma unroll
    for (int i = 0; i < 3; ++i) {
        int q = i * 512 + tid;       // 1536 x 16B chunks
        int row = q / 96, c = q % 96;
        async_copy16((char*)gibuf[0] + q * 16,
                     gi + ((size_t)0 * N_ + n0 + row) * 768 + c * 8);
    }
    for (int t = 0; t < T_; ++t) {
        __syncthreads();   // gi[t] loads + hbf[t&1] writes complete
        if (t + 1 < T_) {
            #pragma unroll
            for (int i = 0; i < 3; ++i) {
                int q = i * 512 + tid;
                int row = q / 96, c = q % 96;
                async_copy16((char*)gibuf[(t + 1) & 1] + q * 16,
                             gi + ((size_t)(t + 1) * N_ + n0 + row) * 768 + c * 8);
            }
        }
        f32x4 acc[3][2] = {};
        const unsigned short* hb = hbf[t & 1];
        #pragma unroll
        for (int kc = 0; kc < 8; ++kc) {
            bf8_t a = *(const bf8_t*)(hb + (lane & 15) * HPAD + kc * 32 + quad * 8);
            #pragma unroll
            for (int g = 0; g < 3; ++g)
                #pragma unroll
                for (int s = 0; s < 2; ++s)
                    acc[g][s] = __builtin_amdgcn_mfma_f32_16x16x32_bf16(
                        a, wf[g][s][kc], acc[g][s], 0, 0, 0);
        }
        const unsigned short* gb = gibuf[t & 1];
        unsigned short* hw = hbf[(t + 1) & 1];
        #pragma unroll
        for (int s = 0; s < 2; ++s) {
            int j = wave * 32 + s * 16 + lj;     // 0..255 within gate
            #pragma unroll
            for (int r = 0; r < 4; ++r) {
                int n = quad * 4 + r;
                float gir = b2f(gb[n * 768 + j]);
                float giz = b2f(gb[n * 768 + 256 + j]);
                float gin = b2f(gb[n * 768 + 512 + j]);
                float rg = fsig(gir + acc[0][s][r] + bh[0][s]);
                float z  = fsig(giz + acc[1][s][r] + bh[1][s]);
                float nn = ftanh_(gin + rg * (acc[2][s][r] + bh[2][s]));
                float h  = (1.f - z) * nn + z * hreg[s][r];
                hreg[s][r] = h;
                hw[n * HPAD + j] = f2b(h);
                size_t orow = (size_t)t * N_ + n0 + n;
                out[orow * 770 + 2 + j] = h;
                h_sbf[orow * 256 + j] = f2b(h);
            }
        }
    }
}

// ---------- phase C: per-n attention  w = K[n] @ k_t,  softmax, probs ----------
__global__ __launch_bounds__(512, 2)
void k_attn(const float* Kmat, const unsigned short* kbf, const float* cc, float* out) {
    int n = blockIdx.x;
    int tid = threadIdx.x, wave = tid >> 6, lane = tid & 63;
    int lt = lane & 15, quad = lane >> 4;
    __shared__ __align__(16) unsigned short sK[128 * HPAD];
    int tg = wave * 16 + lt;                      // this lane's t
    bf8_t bfr[8];
    #pragma unroll
    for (int kc = 0; kc < 8; ++kc)
        bfr[kc] = *(const bf8_t*)(kbf + ((size_t)tg * N_ + n) * H_ + kc * 32 + quad * 8);
    f32x4 acc[16];
    #pragma unroll
    for (int i = 0; i < 16; ++i) acc[i] = (f32x4){0.f, 0.f, 0.f, 0.f};
    for (int half = 0; half < 2; ++half) {
        __syncthreads();
        for (int i = 0; i < 16; ++i) {           // stage 128 K-rows fp32->bf16
            int idx = i * 512 + tid;
            int row = idx >> 6, c4 = idx & 63;
            float4 v = *(const float4*)(Kmat + ((size_t)n * L_ + half * 128 + row) * H_ + c4 * 4);
            ushort4 s4; s4.x = f2b(v.x); s4.y = f2b(v.y); s4.z = f2b(v.z); s4.w = f2b(v.w);
            *(ushort4*)(sK + row * HPAD + c4 * 4) = s4;
        }
        __syncthreads();
        #pragma unroll
        for (int l2 = 0; l2 < 8; ++l2)
            #pragma unroll
            for (int kc = 0; kc < 8; ++kc) {
                bf8_t a = *(const bf8_t*)(sK + (l2 * 16 + lt) * HPAD + kc * 32 + quad * 8);
                acc[half * 8 + l2] = __builtin_amdgcn_mfma_f32_16x16x32_bf16(
                    a, bfr[kc], acc[half * 8 + l2], 0, 0, 0);
            }
    }
    float ccv = cc[(size_t)tg * N_ + n];
    float mx = -3.4e38f;
    #pragma unroll
    for (int i = 0; i < 16; ++i)
        #pragma unroll
        for (int r = 0; r < 4; ++r) { float v = acc[i][r] * ccv; acc[i][r] = v; mx = fmaxf(mx, v); }
    mx = fmaxf(mx, __shfl_xor(mx, 16, 64));
    mx = fmaxf(mx, __shfl_xor(mx, 32, 64));
    float sum = 0.f;
    #pragma unroll
    for (int i = 0; i < 16; ++i)
        #pragma unroll
        for (int r = 0; r < 4; ++r) { float e = __expf(acc[i][r] - mx); acc[i][r] = e; sum += e; }
    sum += __shfl_xor(sum, 16, 64);
    sum += __shfl_xor(sum, 32, 64);
    float inv = frcp(sum);
    float* pbuf = (float*)sK;                     // 64 x 260 floats, reuse LDS
    for (int half = 0; half < 2; ++half) {
        __syncthreads();
        if ((wave >> 2) == half) {
            int trow = (wave & 3) * 16 + lt;
            #pragma unroll
            for (int i = 0; i < 16; ++i)
                #pragma unroll
                for (int r = 0; r < 4; ++r)
                    pbuf[trow * 260 + i * 16 + quad * 4 + r] = acc[i][r] * inv;
        }
        __syncthreads();
        for (int i = 0; i < 16; ++i) {           // coalesced copy-out as float2
            int idx = i * 512 + tid;
            int trow = idx >> 7, c2 = idx & 127;
            float2 v = *(const float2*)(pbuf + trow * 260 + c2 * 2);
            int t = half * 64 + trow;
            *(float2*)(out + ((size_t)t * N_ + n) * 770 + 258 + c2 * 2) = v;
        }
    }
}

// ---------- epilogue scalars ----------
__global__ void k_va(const float* Wc, const float* bc, const int* act, float* out) {
    int gw = blockIdx.x * 4 + (threadIdx.x >> 6);
    int lane = threadIdx.x & 63;
    const float* h = out + (size_t)gw * 770 + 2;
    float s = 0.f;
    #pragma unroll
    for (int i = 0; i < 4; ++i) { int j = i * 64 + lane; s += h[j] * Wc[j]; }
    #pragma unroll
    for (int off = 32; off; off >>= 1) s += __shfl_down(s, off, 64);
    if (lane == 0) {
        out[(size_t)gw * 770 + 1] = s + bc[0];
        out[(size_t)gw * 770 + 0] = (float)act[gw];
    }
}
__global__ void k_ph(const int* act, float* out) {
    int idx = blockIdx.x * 256 + threadIdx.x;    // m*256 + l
    int m = idx >> 8, l = idx & 255;
    out[(size_t)m * 770 + 514 + l] = (l == act[m]) ? 1.f : 0.f;
}

extern "C" void kernel_launch(void* const* d_in, const int* in_sizes, int n_in,
                              void* d_out, int out_size, void* d_ws, size_t ws_size,
                              hipStream_t stream) {
    (void)in_sizes; (void)n_in; (void)out_size; (void)ws_size;
    const float* cond = (const float*)d_in[0];
    const float* M    = (const float*)d_in[1];
    const float* Km   = (const float*)d_in[2];
    const float* C    = (const float*)d_in[3];
    const float* h0   = (const float*)d_in[4];
    const float* p0   = (const float*)d_in[5];
    const float* W0   = (const float*)d_in[6];
    const float* b0   = (const float*)d_in[7];
    const float* W1   = (const float*)d_in[8];
    const float* b1   = (const float*)d_in[9];
    const float* W2   = (const float*)d_in[10];
    const float* b2   = (const float*)d_in[11];
    const float* Wih  = (const float*)d_in[12];
    const float* Whh  = (const float*)d_in[13];
    const float* bih  = (const float*)d_in[14];
    const float* bhh  = (const float*)d_in[15];
    const float* Wa   = (const float*)d_in[16];
    const float* ba   = (const float*)d_in[17];
    const float* Wc   = (const float*)d_in[18];
    const float* bc   = (const float*)d_in[19];
    const int*   act  = (const int*)d_in[20];
    float* out = (float*)d_out;
    char* ws = (char*)d_ws;

    size_t o_xin  = 0;                       // 32768*320*2
    size_t o_actA = 20971520;                // 32768*256*2
    size_t o_actB = 37748736;                // 32768*256*2
    size_t o_gi   = 54525952;                // 32768*768*2
    size_t o_w0t  = 104857600;               // 256*320*2
    size_t o_w1t  = o_w0t + 163840;
    size_t o_w2t  = o_w1t + 131072;
    size_t o_wih  = o_w2t + 131072;          // 768*256*2
    size_t o_wat  = o_wih + 393216;
    size_t o_whh  = o_wat + 131072;          // 768*256*2
    size_t o_r0   = o_whh + 393216;          // 256*256*4
    size_t o_cc0  = o_r0 + 262144;           // 256*4
    size_t o_cc   = o_cc0 + 1024;            // 32768*4
    size_t o_hsbf = o_actB;                  // reuse (x1 dead after L3... used after L4)
    size_t o_kbf  = o_actA;                  // reuse (x2 dead after L4)

    unsigned short* xin  = (unsigned short*)(ws + o_xin);
    unsigned short* actA = (unsigned short*)(ws + o_actA);
    unsigned short* actB = (unsigned short*)(ws + o_actB);
    unsigned short* gi   = (unsigned short*)(ws + o_gi);
    unsigned short* w0t  = (unsigned short*)(ws + o_w0t);
    unsigned short* w1t  = (unsigned short*)(ws + o_w1t);
    unsigned short* w2t  = (unsigned short*)(ws + o_w2t);
    unsigned short* wihb = (unsigned short*)(ws + o_wih);
    unsigned short* watb = (unsigned short*)(ws + o_wat);
    unsigned short* whhb = (unsigned short*)(ws + o_whh);
    float* r0  = (float*)(ws + o_r0);
    float* cc0 = (float*)(ws + o_cc0);
    float* cc  = (float*)(ws + o_cc);
    unsigned short* hsbf = (unsigned short*)(ws + o_hsbf);
    unsigned short* kbf  = (unsigned short*)(ws + o_kbf);

    // weight prep
    k_tcast<<<320, 256, 0, stream>>>(W0, w0t, 320, 256);
    k_tcast<<<256, 256, 0, stream>>>(W1, w1t, 256, 256);
    k_tcast<<<256, 256, 0, stream>>>(W2, w2t, 256, 256);
    k_tcast<<<256, 256, 0, stream>>>(Wa, watb, 256, 256);
    k_cast<<<768, 256, 0, stream>>>(Wih, wihb, 768 * 256);
    k_cast<<<768, 256, 0, stream>>>(Whh, whhb, 768 * 256);
    // t=0 dense read + cc + xin
    k_r0<<<256, 256, 0, stream>>>(M, C, p0, r0, cc0);
    k_cc<<<128, 256, 0, stream>>>(C, act, cc0, cc);
    k_xin<<<40960, 256, 0, stream>>>(cond, M, r0, act, xin);
    // MLP chain + gi
    k_gemm<1><<<dim3(2, 256), 256, 0, stream>>>(xin,  w0t,  b0,  actA, 256, 320);
    k_gemm<1><<<dim3(2, 256), 256, 0, stream>>>(actA, w1t,  b1,  actB, 256, 256);
    k_gemm<1><<<dim3(2, 256), 256, 0, stream>>>(actB, w2t,  b2,  actA, 256, 256);
    k_gemm<0><<<dim3(6, 256), 256, 0, stream>>>(actA, wihb, bih, gi,   768, 256);
    // sequential GRU
    k_gru<<<16, 512, 0, stream>>>(gi, whhb, bhh, h0, out, hsbf);
    // k = h @ Wa + ba
    k_gemm<0><<<dim3(2, 256), 256, 0, stream>>>(hsbf, watb, ba, kbf, 256, 256);
    // v, a, one-hot p, attention probs
    k_va<<<8192, 256, 0, stream>>>(Wc, bc, act, out);
    k_ph<<<32768, 256, 0, stream>>>(act, out);
    k_attn<<<256, 512, 0, stream>>>(Km, kbf, cc, out);
}

// Round 2
// 608.644 us; speedup vs baseline: 1.1863x; 1.1863x over previous
//
#include <hip/hip_runtime.h>
#include <hip/hip_bf16.h>

#define T_ 128
#define N_ 256
#define L_ 256
#define H_ 256
#define COND_ 64

typedef __bf16 bf8_t __attribute__((ext_vector_type(8)));
typedef float f32x4 __attribute__((ext_vector_type(4)));

__device__ __forceinline__ float b2f(unsigned short s) {
    union { unsigned int u; float f; } v; v.u = ((unsigned int)s) << 16; return v.f;
}
__device__ __forceinline__ unsigned short f2b(float f) {
    union { float f; unsigned int u; } v; v.f = f;
    unsigned int r = v.u + 0x7fffu + ((v.u >> 16) & 1u);
    return (unsigned short)(r >> 16);
}
__device__ __forceinline__ void async_copy16(void* lds, const void* g) {
    __builtin_amdgcn_global_load_lds(
        (const __attribute__((address_space(1))) unsigned int*)g,
        (__attribute__((address_space(3))) unsigned int*)lds, 16, 0, 0);
}
__device__ __forceinline__ float frcp(float x) { return __builtin_amdgcn_rcpf(x); }
__device__ __forceinline__ float fsig(float x) { return frcp(1.f + __expf(-x)); }
__device__ __forceinline__ float ftanh_(float x) { return 2.f * fsig(2.f * x) - 1.f; }

// ---------- small prep kernels ----------
__global__ void k_cast(const float* W, unsigned short* O, int n) {
    int i = blockIdx.x * 256 + threadIdx.x;
    if (i < n) O[i] = f2b(W[i]);
}
// fp8 e4m3 cast (4 values per thread)
__global__ void k_cast8(const float* W, unsigned char* O, int n4) {
    int i = blockIdx.x * 256 + threadIdx.x;
    if (i < n4) {
        float4 w = *(const float4*)(W + (size_t)i * 4);
        int pk = __builtin_amdgcn_cvt_pk_fp8_f32(w.x, w.y, 0, false);
        pk = __builtin_amdgcn_cvt_pk_fp8_f32(w.z, w.w, pk, true);
        ((int*)O)[i] = pk;
    }
}
// b3 = bih + bhh (bias fold)
__global__ void k_bsum(const float* a, const float* b, float* o, int n) {
    int i = blockIdx.x * 256 + threadIdx.x;
    if (i < n) o[i] = a[i] + b[i];
}
// Wt[j][k] = bf16(W[k][j]); W is Kd x Jd row-major
__global__ void k_tcast(const float* W, unsigned short* Wt, int Kd, int Jd) {
    int idx = blockIdx.x * 256 + threadIdx.x;
    if (idx >= Kd * Jd) return;
    int j = idx / Kd, k = idx % Kd;
    Wt[idx] = f2b(W[k * Jd + j]);
}
// dense t=0 read: r0 = p_init @ M, cc0 = p_init . C
__global__ void k_r0(const float* M, const float* C, const float* p0,
                     float* r0, float* cc0) {
    int n = blockIdx.x; int tid = threadIdx.x;
    __shared__ float pinit[L_];
    __shared__ float red[256];
    __shared__ int nz;
    if (tid == 0) nz = 0;
    __syncthreads();
    float p = p0[n * L_ + tid];
    if (p != 0.f) atomicAdd(&nz, 1);
    pinit[tid] = p;
    __syncthreads();
    if (tid == 0 && nz == 0) pinit[0] = 1.0f;
    __syncthreads();
    float acc = 0.f;
    for (int l = 0; l < L_; ++l) {
        float s = pinit[l];
        if (s != 0.f) acc += s * M[((size_t)n * L_ + l) * H_ + tid];
    }
    r0[n * H_ + tid] = acc;
    red[tid] = pinit[tid] * C[n * L_ + tid];
    __syncthreads();
    for (int s = 128; s > 0; s >>= 1) { if (tid < s) red[tid] += red[tid + s]; __syncthreads(); }
    if (tid == 0) cc0[n] = red[0];
}
__global__ void k_cc(const float* C, const int* act, const float* cc0, float* cc) {
    int idx = blockIdx.x * 256 + threadIdx.x;
    int t = idx / N_, n = idx % N_;
    cc[idx] = (t == 0) ? cc0[n] : C[n * L_ + act[(t - 1) * N_ + n]];
}
// xin[m][0:64]=cond, [64:320]=r (gather / dense t=0), bf16
__global__ void k_xin(const float* cond, const float* M, const float* r0,
                      const int* act, unsigned short* xin) {
    int idx = blockIdx.x * 256 + threadIdx.x;   // m*320+j
    int m = idx / 320, j = idx % 320;
    int t = m / N_, n = m % N_;
    float v;
    if (j < COND_) v = cond[(size_t)m * COND_ + j];
    else {
        int h = j - COND_;
        v = (t == 0) ? r0[n * H_ + h]
                     : M[((size_t)n * L_ + act[(t - 1) * N_ + n]) * H_ + h];
    }
    xin[(size_t)m * 320 + j] = f2b(v);
}

// ---------- bf16 MFMA GEMM: D = act(A @ Bt^T + bias), A[M][K], Bt[N][K] ----------
template<int RELU>
__global__ __launch_bounds__(256, 2)
void k_gemm(const unsigned short* A, const unsigned short* Bt, const float* bias,
            unsigned short* D, int Ndim, int Kdim) {
    __shared__ __align__(16) unsigned short sA[128 * 64];
    __shared__ __align__(16) unsigned short sB[128 * 64];
    int tid = threadIdx.x;
    int m0 = blockIdx.y * 128, n0 = blockIdx.x * 128;
    int wave = tid >> 6, lane = tid & 63;
    int wm = (wave & 1) * 64, wn = (wave >> 1) * 64;
    int lrow = lane & 15, quad = lane >> 4;
    f32x4 acc[4][4] = {};
    int kIters = Kdim / 64;
    for (int kt = 0; kt < kIters; ++kt) {
        __syncthreads();
        #pragma unroll
        for (int i = 0; i < 4; ++i) {
            int q = i * 256 + tid;
            int row = q >> 3, c = q & 7, sc = c ^ (row & 7);
            async_copy16((char*)sA + q * 16,
                         A + (size_t)(m0 + row) * Kdim + kt * 64 + sc * 8);
        }
        #pragma unroll
        for (int i = 0; i < 4; ++i) {
            int q = i * 256 + tid;
            int row = q >> 3, c = q & 7, sc = c ^ (row & 7);
            async_copy16((char*)sB + q * 16,
                         Bt + (size_t)(n0 + row) * Kdim + kt * 64 + sc * 8);
        }
        __syncthreads();
        #pragma unroll
        for (int kc = 0; kc < 2; ++kc) {
            bf8_t af[4], bfr[4];
            #pragma unroll
            for (int mt = 0; mt < 4; ++mt) {
                int row = wm + mt * 16 + lrow;
                int phys = (kc * 4 + quad) ^ (row & 7);
                af[mt] = *(const bf8_t*)(sA + row * 64 + phys * 8);
            }
            #pragma unroll
            for (int nt = 0; nt < 4; ++nt) {
                int row = wn + nt * 16 + lrow;
                int phys = (kc * 4 + quad) ^ (row & 7);
                bfr[nt] = *(const bf8_t*)(sB + row * 64 + phys * 8);
            }
            #pragma unroll
            for (int mt = 0; mt < 4; ++mt)
                #pragma unroll
                for (int nt = 0; nt < 4; ++nt)
                    acc[mt][nt] = __builtin_amdgcn_mfma_f32_16x16x32_bf16(
                        af[mt], bfr[nt], acc[mt][nt], 0, 0, 0);
        }
    }
    #pragma unroll
    for (int nt = 0; nt < 4; ++nt) {
        int ncol = n0 + wn + nt * 16 + lrow;
        float bv = bias[ncol];
        #pragma unroll
        for (int mt = 0; mt < 4; ++mt)
            #pragma unroll
            for (int r = 0; r < 4; ++r) {
                int mrow = m0 + wm + mt * 16 + quad * 4 + r;
                float v = acc[mt][nt][r] + bv;
                if (RELU) v = v > 0.f ? v : 0.f;
                D[(size_t)mrow * Ndim + ncol] = f2b(v);
            }
    }
}

// ---------- phase B: sequential GRU, 16 blocks x 16 rows, 16 waves ----------
// W_hh in fp8 e4m3 -> register-resident B-fragments (48 VGPR/lane).
// No global stores of out[] in the loop; h copied out coalesced from LDS.
#define HP8 264     // fp8 h row pad (bytes)
#define HPB 264     // bf16 h row pad (shorts)
__global__ __launch_bounds__(1024, 4)
void k_gru(const unsigned short* gi, const unsigned char* Whh8,
           const float* h0, unsigned short* h_sbf) {
    int n0 = blockIdx.x * 16;
    int tid = threadIdx.x, wave = tid >> 6, lane = tid & 63;
    int lj = lane & 15, quad = lane >> 4;
    __shared__ __align__(16) unsigned short gibuf[2][16 * 768];   // 49152 B
    __shared__ __align__(16) unsigned char  h8b[2][16 * HP8];     // 8448 B
    __shared__ __align__(16) unsigned short hbb[2][16 * HPB];     // 16896 B
    int j = wave * 16 + lj;              // this lane's gate column (0..255)
    // register-resident W_hh fp8 fragments: B[k][col=j], k = kc*32 + quad*8 + i
    long wf[3][8];
    #pragma unroll
    for (int g = 0; g < 3; ++g)
        #pragma unroll
        for (int kc = 0; kc < 8; ++kc)
            wf[g][kc] = *(const long*)(Whh8 + (size_t)(g * 256 + j) * 256 + kc * 32 + quad * 8);
    float hreg[4];
    #pragma unroll
    for (int r = 0; r < 4; ++r)
        hreg[r] = h0[(size_t)(n0 + quad * 4 + r) * 256 + j];
    // stage h0 -> h8b[0] (fp8), 4 bytes/thread
    {
        int n = tid >> 6, c = (tid & 63) * 4;
        float4 hv = *(const float4*)(h0 + (size_t)(n0 + n) * 256 + c);
        int pk = __builtin_amdgcn_cvt_pk_fp8_f32(hv.x, hv.y, 0, false);
        pk = __builtin_amdgcn_cvt_pk_fp8_f32(hv.z, hv.w, pk, true);
        *(int*)(h8b[0] + n * HP8 + c) = pk;
    }
    // prefetch pointers (1536 16B chunks, threads 0..511 take a second chunk)
    int q0 = tid, q1 = 1024 + tid;
    const unsigned short* gp0 = gi + (size_t)(n0 + q0 / 96) * 768 + (q0 % 96) * 8;
    const unsigned short* gp1 = gi + (size_t)(n0 + q1 / 96) * 768 + (q1 % 96) * 8;
    int lo0 = q0 * 16, lo1 = q1 * 16;
    // prefetch gi[0]
    async_copy16((char*)gibuf[0] + lo0, gp0);
    if (tid < 512) async_copy16((char*)gibuf[0] + lo1, gp1);

    int con = tid >> 6, coc = (tid & 63) * 4;      // copy-out mapping
    for (int t = 0; t < T_; ++t) {
        __syncthreads();      // gi[t] + h writes of t-1 complete
        // copy out h_{t-1} (coalesced 8B per thread)
        if (t > 0) {
            long v = *(const long*)(&hbb[t & 1][con * HPB + coc]);
            *(long*)(h_sbf + ((size_t)(t - 1) * N_ + n0 + con) * 256 + coc) = v;
        }
        // prefetch gi[t+1]
        if (t + 1 < T_) {
            size_t toff = (size_t)(t + 1) * N_ * 768;
            async_copy16((char*)gibuf[(t + 1) & 1] + lo0, gp0 + toff);
            if (tid < 512) async_copy16((char*)gibuf[(t + 1) & 1] + lo1, gp1 + toff);
        }
        // gh = h @ Whh^T : fp8 MFMA, A[m=n][k], B resident
        f32x4 acc[3] = {};
        const unsigned char* hb = h8b[t & 1];
        #pragma unroll
        for (int kc = 0; kc < 8; ++kc) {
            long a = *(const long*)(hb + lj * HP8 + kc * 32 + quad * 8);
            #pragma unroll
            for (int g = 0; g < 3; ++g)
                acc[g] = __builtin_amdgcn_mfma_f32_16x16x32_fp8_fp8(a, wf[g][kc], acc[g], 0, 0, 0);
        }
        // gate math (bias bhh pre-folded into gi)
        const unsigned short* gb = gibuf[t & 1];
        unsigned char* h8w = h8b[(t + 1) & 1];
        unsigned short* hbw = hbb[(t + 1) & 1];
        #pragma unroll
        for (int r = 0; r < 4; ++r) {
            int n = quad * 4 + r;
            float gir = b2f(gb[n * 768 + j]);
            float giz = b2f(gb[n * 768 + 256 + j]);
            float gin = b2f(gb[n * 768 + 512 + j]);
            float rg = fsig(gir + acc[0][r]);
            float z  = fsig(giz + acc[1][r]);
            float nn = ftanh_(gin + rg * acc[2][r]);
            float h  = nn + z * (hreg[r] - nn);
            hreg[r] = h;
            int pk = __builtin_amdgcn_cvt_pk_fp8_f32(h, h, 0, false);
            h8w[n * HP8 + j] = (unsigned char)pk;
            hbw[n * HPB + j] = f2b(h);
        }
    }
    __syncthreads();
    // final copy: h_127 lives in hbb[0]
    long v = *(const long*)(&hbb[0][con * HPB + coc]);
    *(long*)(h_sbf + ((size_t)127 * N_ + n0 + con) * 256 + coc) = v;
}

// ---------- phase C: per-n attention  w = K[n] @ k_t,  softmax, probs ----------
#define HPAD 280
__global__ __launch_bounds__(512, 2)
void k_attn(const float* Kmat, const unsigned short* kbf, const float* cc, float* out) {
    int n = blockIdx.x;
    int tid = threadIdx.x, wave = tid >> 6, lane = tid & 63;
    int lt = lane & 15, quad = lane >> 4;
    __shared__ __align__(16) unsigned short sK[128 * HPAD];
    int tg = wave * 16 + lt;
    bf8_t bfr[8];
    #pragma unroll
    for (int kc = 0; kc < 8; ++kc)
        bfr[kc] = *(const bf8_t*)(kbf + ((size_t)tg * N_ + n) * H_ + kc * 32 + quad * 8);
    f32x4 acc[16];
    #pragma unroll
    for (int i = 0; i < 16; ++i) acc[i] = (f32x4){0.f, 0.f, 0.f, 0.f};
    for (int half = 0; half < 2; ++half) {
        __syncthreads();
        for (int i = 0; i < 16; ++i) {
            int idx = i * 512 + tid;
            int row = idx >> 6, c4 = idx & 63;
            float4 v = *(const float4*)(Kmat + ((size_t)n * L_ + half * 128 + row) * H_ + c4 * 4);
            ushort4 s4; s4.x = f2b(v.x); s4.y = f2b(v.y); s4.z = f2b(v.z); s4.w = f2b(v.w);
            *(ushort4*)(sK + row * HPAD + c4 * 4) = s4;
        }
        __syncthreads();
        #pragma unroll
        for (int l2 = 0; l2 < 8; ++l2)
            #pragma unroll
            for (int kc = 0; kc < 8; ++kc) {
                bf8_t a = *(const bf8_t*)(sK + (l2 * 16 + lt) * HPAD + kc * 32 + quad * 8);
                acc[half * 8 + l2] = __builtin_amdgcn_mfma_f32_16x16x32_bf16(
                    a, bfr[kc], acc[half * 8 + l2], 0, 0, 0);
            }
    }
    float ccv = cc[(size_t)tg * N_ + n];
    float mx = -3.4e38f;
    #pragma unroll
    for (int i = 0; i < 16; ++i)
        #pragma unroll
        for (int r = 0; r < 4; ++r) { float v = acc[i][r] * ccv; acc[i][r] = v; mx = fmaxf(mx, v); }
    mx = fmaxf(mx, __shfl_xor(mx, 16, 64));
    mx = fmaxf(mx, __shfl_xor(mx, 32, 64));
    float sum = 0.f;
    #pragma unroll
    for (int i = 0; i < 16; ++i)
        #pragma unroll
        for (int r = 0; r < 4; ++r) { float e = __expf(acc[i][r] - mx); acc[i][r] = e; sum += e; }
    sum += __shfl_xor(sum, 16, 64);
    sum += __shfl_xor(sum, 32, 64);
    float inv = frcp(sum);
    float* pbuf = (float*)sK;
    for (int half = 0; half < 2; ++half) {
        __syncthreads();
        if ((wave >> 2) == half) {
            int trow = (wave & 3) * 16 + lt;
            #pragma unroll
            for (int i = 0; i < 16; ++i)
                #pragma unroll
                for (int r = 0; r < 4; ++r)
                    pbuf[trow * 260 + i * 16 + quad * 4 + r] = acc[i][r] * inv;
        }
        __syncthreads();
        for (int i = 0; i < 16; ++i) {
            int idx = i * 512 + tid;
            int trow = idx >> 7, c2 = idx & 127;
            float2 v = *(const float2*)(pbuf + trow * 260 + c2 * 2);
            int t = half * 64 + trow;
            *(float2*)(out + ((size_t)t * N_ + n) * 770 + 258 + c2 * 2) = v;
        }
    }
}

// ---------- epilogue: a, v, h(fp32 expand) ----------
__global__ void k_vah(const unsigned short* h_sbf, const float* Wc, const float* bc,
                      const int* act, float* out) {
    int gw = blockIdx.x * 4 + (threadIdx.x >> 6);   // row t*N+n
    int lane = threadIdx.x & 63;
    const unsigned short* hrow = h_sbf + (size_t)gw * 256;
    float* orow = out + (size_t)gw * 770;
    float4 wv = *(const float4*)(Wc + lane * 4);
    ushort4 hv = *(const ushort4*)(hrow + lane * 4);
    float h0f = b2f(hv.x), h1f = b2f(hv.y), h2f = b2f(hv.z), h3f = b2f(hv.w);
    float s = h0f * wv.x + h1f * wv.y + h2f * wv.z + h3f * wv.w;
    *(float2*)(orow + 2 + lane * 4) = make_float2(h0f, h1f);
    *(float2*)(orow + 4 + lane * 4) = make_float2(h2f, h3f);
    #pragma unroll
    for (int off = 32; off; off >>= 1) s += __shfl_down(s, off, 64);
    if (lane == 0) {
        orow[1] = s + bc[0];
        orow[0] = (float)act[gw];
    }
}
__global__ void k_ph(const int* act, float* out) {
    int idx = blockIdx.x * 256 + threadIdx.x;    // m*256 + l
    int m = idx >> 8, l = idx & 255;
    out[(size_t)m * 770 + 514 + l] = (l == act[m]) ? 1.f : 0.f;
}

extern "C" void kernel_launch(void* const* d_in, const int* in_sizes, int n_in,
                              void* d_out, int out_size, void* d_ws, size_t ws_size,
                              hipStream_t stream) {
    (void)in_sizes; (void)n_in; (void)out_size; (void)ws_size;
    const float* cond = (const float*)d_in[0];
    const float* M    = (const float*)d_in[1];
    const float* Km   = (const float*)d_in[2];
    const float* C    = (const float*)d_in[3];
    const float* h0   = (const float*)d_in[4];
    const float* p0   = (const float*)d_in[5];
    const float* W0   = (const float*)d_in[6];
    const float* b0   = (const float*)d_in[7];
    const float* W1   = (const float*)d_in[8];
    const float* b1   = (const float*)d_in[9];
    const float* W2   = (const float*)d_in[10];
    const float* b2   = (const float*)d_in[11];
    const float* Wih  = (const float*)d_in[12];
    const float* Whh  = (const float*)d_in[13];
    const float* bih  = (const float*)d_in[14];
    const float* bhh  = (const float*)d_in[15];
    const float* Wa   = (const float*)d_in[16];
    const float* ba   = (const float*)d_in[17];
    const float* Wc   = (const float*)d_in[18];
    const float* bc   = (const float*)d_in[19];
    const int*   act  = (const int*)d_in[20];
    float* out = (float*)d_out;
    char* ws = (char*)d_ws;

    size_t o_xin  = 0;                       // 32768*320*2
    size_t o_actA = 20971520;
    size_t o_actB = 37748736;
    size_t o_gi   = 54525952;                // 32768*768*2
    size_t o_w0t  = 104857600;
    size_t o_w1t  = o_w0t + 163840;
    size_t o_w2t  = o_w1t + 131072;
    size_t o_wih  = o_w2t + 131072;          // 768*256*2
    size_t o_wat  = o_wih + 393216;
    size_t o_whh8 = o_wat + 131072;          // 768*256*1 fp8
    size_t o_r0   = o_whh8 + 393216;         // 256*256*4 (b3 overlays after k_xin)
    size_t o_cc0  = o_r0 + 262144;
    size_t o_cc   = o_cc0 + 1024;
    size_t o_hsbf = o_actB;                  // reuse
    size_t o_kbf  = o_actA;                  // reuse
    size_t o_b3   = o_r0;                    // reuse after k_xin

    unsigned short* xin  = (unsigned short*)(ws + o_xin);
    unsigned short* actA = (unsigned short*)(ws + o_actA);
    unsigned short* actB = (unsigned short*)(ws + o_actB);
    unsigned short* gi   = (unsigned short*)(ws + o_gi);
    unsigned short* w0t  = (unsigned short*)(ws + o_w0t);
    unsigned short* w1t  = (unsigned short*)(ws + o_w1t);
    unsigned short* w2t  = (unsigned short*)(ws + o_w2t);
    unsigned short* wihb = (unsigned short*)(ws + o_wih);
    unsigned short* watb = (unsigned short*)(ws + o_wat);
    unsigned char*  whh8 = (unsigned char*)(ws + o_whh8);
    float* r0  = (float*)(ws + o_r0);
    float* cc0 = (float*)(ws + o_cc0);
    float* cc  = (float*)(ws + o_cc);
    float* b3  = (float*)(ws + o_b3);
    unsigned short* hsbf = (unsigned short*)(ws + o_hsbf);
    unsigned short* kbf  = (unsigned short*)(ws + o_kbf);

    // weight prep
    k_tcast<<<320, 256, 0, stream>>>(W0, w0t, 320, 256);
    k_tcast<<<256, 256, 0, stream>>>(W1, w1t, 256, 256);
    k_tcast<<<256, 256, 0, stream>>>(W2, w2t, 256, 256);
    k_tcast<<<256, 256, 0, stream>>>(Wa, watb, 256, 256);
    k_cast<<<768, 256, 0, stream>>>(Wih, wihb, 768 * 256);
    k_cast8<<<192, 256, 0, stream>>>(Whh, whh8, 768 * 256 / 4);
    // t=0 dense read + cc + xin (r0 alive only until k_xin)
    k_r0<<<256, 256, 0, stream>>>(M, C, p0, r0, cc0);
    k_cc<<<128, 256, 0, stream>>>(C, act, cc0, cc);
    k_xin<<<40960, 256, 0, stream>>>(cond, M, r0, act, xin);
    k_bsum<<<3, 256, 0, stream>>>(bih, bhh, b3, 768);
    // MLP chain + gi (bias = bih + bhh folded)
    k_gemm<1><<<dim3(2, 256), 256, 0, stream>>>(xin,  w0t,  b0, actA, 256, 320);
    k_gemm<1><<<dim3(2, 256), 256, 0, stream>>>(actA, w1t,  b1, actB, 256, 256);
    k_gemm<1><<<dim3(2, 256), 256, 0, stream>>>(actB, w2t,  b2, actA, 256, 256);
    k_gemm<0><<<dim3(6, 256), 256, 0, stream>>>(actA, wihb, b3, gi,   768, 256);
    // sequential GRU
    k_gru<<<16, 1024, 0, stream>>>(gi, whh8, h0, hsbf);
    // k = h @ Wa + ba
    k_gemm<0><<<dim3(2, 256), 256, 0, stream>>>(hsbf, watb, ba, kbf, 256, 256);
    // epilogue
    k_vah<<<8192, 256, 0, stream>>>(hsbf, Wc, bc, act, out);
    k_ph<<<32768, 256, 0, stream>>>(act, out);
    k_attn<<<256, 512, 0, stream>>>(Km, kbf, cc, out);
}